// Round 15
// baseline (906.416 us; speedup 1.0000x reference)
//
#include <hip/hip_runtime.h>
#include <hip/hip_bf16.h>

#define TPB   512
#define CDIM  192
#define LD    200    // shorts; leading dim for both LDS buffers
#define SCALE 0.07216878364870323f  // 1/sqrt(192)
#define EPSF  1e-12f

using short8 = __attribute__((ext_vector_type(8))) short;
using f32x4  = __attribute__((ext_vector_type(4))) float;
using us4    = __attribute__((ext_vector_type(4))) unsigned short;

__device__ __forceinline__ unsigned short hc(float f) {
  __hip_bfloat16 h = __float2bfloat16(f);
  unsigned short u; __builtin_memcpy(&u, &h, 2); return u;
}
__device__ __forceinline__ unsigned pack2(float x, float y) {
  return (unsigned)hc(x) | ((unsigned)hc(y) << 16);
}
#define MFMA(a, b, c) __builtin_amdgcn_mfma_f32_16x16x32_bf16((a), (b), (c), 0, 0, 0)
#define SCHED_FENCE() __builtin_amdgcn_sched_barrier(0)

// ---- pre-kernel: cast weights f32 -> bf16 into workspace ----
#define NWQ  36864
#define NWKV 73728
#define NWP  36864
__global__ void cvt_weights(const float* __restrict__ Wq, const float* __restrict__ Wkv,
                            const float* __restrict__ Wp, unsigned short* __restrict__ o) {
  int i = blockIdx.x * blockDim.x + threadIdx.x;
  if (i < NWQ) o[i] = hc(Wq[i]);
  else if (i < NWQ + NWKV) o[i] = hc(Wkv[i - NWQ]);
  else if (i < NWQ + NWKV + NWP) o[i] = hc(Wp[i - NWQ - NWKV]);
}

// One block per kv-window; q-windows {b + j*BKV}. kv staged once (sKV, immutable);
// K/V projections recomputed per window from sKV (no frags held across phases).
__global__ __launch_bounds__(TPB, 4) void wa_v15(
    const float* __restrict__ qx, const float* __restrict__ kvx,
    const float* __restrict__ pos,
    const float* __restrict__ bq, const float* __restrict__ bkv,
    const float* __restrict__ bp,
    const unsigned short* __restrict__ Wqb, const unsigned short* __restrict__ Wkvb,
    const unsigned short* __restrict__ Wpb,
    float* __restrict__ out, int BKV, int tile_num)
{
  __shared__ __align__(16) unsigned short sQX[64 * LD];  // qx+pos staging -> x (per window)
  __shared__ __align__(16) unsigned short sKV[64 * LD];  // kvx staging (immutable)

  const int tid = threadIdx.x;
  const int wid = tid >> 6;          // 0..7; waves 0..5 are head-waves
  const int l15 = (tid & 63) & 15;
  const int l4  = (tid & 63) >> 4;
  const int b   = blockIdx.x;
  const size_t kvoff = (size_t)b * (64 * CDIM);

  const int srcA = l15 + 32 * (l4 & 1);
  const int srcB = srcA + 16;
  const int sel  = l4 >> 1;
  auto redistC = [&](f32x4 cA, f32x4 cB) -> short8 {
    unsigned iA0 = pack2(cA[0], cA[1]), iA1 = pack2(cA[2], cA[3]);
    unsigned iB0 = pack2(cB[0], cB[1]), iB1 = pack2(cB[2], cB[3]);
    unsigned A00 = (unsigned)__shfl((int)iA0, srcA);
    unsigned A01 = (unsigned)__shfl((int)iA1, srcA);
    unsigned A10 = (unsigned)__shfl((int)iB0, srcA);
    unsigned A11 = (unsigned)__shfl((int)iB1, srcA);
    unsigned B00 = (unsigned)__shfl((int)iA0, srcB);
    unsigned B01 = (unsigned)__shfl((int)iA1, srcB);
    unsigned B10 = (unsigned)__shfl((int)iB0, srcB);
    unsigned B11 = (unsigned)__shfl((int)iB1, srcB);
    union { uint4 u; short8 s; } uu;
    uu.u.x = sel ? A10 : A00;
    uu.u.y = sel ? A11 : A01;
    uu.u.z = sel ? B10 : B00;
    uu.u.w = sel ? B11 : B01;
    return uu.s;
  };

  const int h = wid;   // head for waves 0..5

  // ============ pre-loop: issue window-0 qx loads; stage kvx -> sKV ============
  float4 pre[6];
  {
    const float4* gq = (const float4*)(qx + kvoff);   // window 0 == kv offset
    #pragma unroll
    for (int t = 0; t < 6; ++t) pre[t] = gq[tid + t * TPB];
    const float4* gk = (const float4*)(kvx + kvoff);
    #pragma unroll
    for (int t = 0; t < 6; ++t) {
      int e = tid + t * TPB, row = e / 48, c4 = e % 48;
      float4 k = gk[e];
      us4 wk; wk.x = hc(k.x); wk.y = hc(k.y); wk.z = hc(k.z); wk.w = hc(k.w);
      *(us4*)&sKV[row * LD + c4 * 4] = wk;
    }
  }
  __syncthreads();

  for (int w = 0; w < tile_num; ++w) {
    const size_t qoff = kvoff + (size_t)w * BKV * (64 * CDIM);

    // ---- loop-top: convert held qx (+pos from L2) -> sQX ----
    {
      const float4* p4 = (const float4*)pos;
      #pragma unroll
      for (int t = 0; t < 6; ++t) {
        int e = tid + t * TPB, row = e / 48, c4 = e % 48;
        float4 p = p4[e];
        us4 wq;
        wq.x = hc(pre[t].x + p.x); wq.y = hc(pre[t].y + p.y);
        wq.z = hc(pre[t].z + p.z); wq.w = hc(pre[t].w + p.w);
        *(us4*)&sQX[row * LD + c4 * 4] = wq;
      }
    }

    // ---- kproj + vproj from sKV (head-waves); results in regs ----
    short8 kres[4];      // QK A-frag, tile n
    short8 av[2][2];     // PV A-frags (V^T)
    if (wid < 6) {
      {
        f32x4 kacc[4][2];
        #pragma unroll
        for (int mh = 0; mh < 2; ++mh) {
          float4 bk = *(const float4*)&bkv[32 * h + 16 * mh + 4 * l4];
          #pragma unroll
          for (int n = 0; n < 4; ++n) kacc[n][mh] = f32x4{bk.x, bk.y, bk.z, bk.w};
        }
        #pragma unroll
        for (int ks = 0; ks < 6; ++ks) {
          short8 act[4];
          #pragma unroll
          for (int n = 0; n < 4; ++n)
            act[n] = *(const short8*)&sKV[(16 * n + l15) * LD + ks * 32 + 8 * l4];
          #pragma unroll
          for (int mh = 0; mh < 2; ++mh) {
            short8 kw = *(const short8*)&Wkvb[(size_t)(32 * h + 16 * mh + l15) * CDIM + ks * 32 + 8 * l4];
            #pragma unroll
            for (int n = 0; n < 4; ++n) kacc[n][mh] = MFMA(kw, act[n], kacc[n][mh]);
          }
        }
        #pragma unroll
        for (int n = 0; n < 4; ++n) {
          float ss = 0.f;
          #pragma unroll
          for (int mh = 0; mh < 2; ++mh)
            #pragma unroll
            for (int r = 0; r < 4; ++r) ss += kacc[n][mh][r] * kacc[n][mh][r];
          ss += __shfl_xor(ss, 16);
          ss += __shfl_xor(ss, 32);
          float sc = 1.0f / fmaxf(sqrtf(ss), EPSF);
          #pragma unroll
          for (int mh = 0; mh < 2; ++mh)
            #pragma unroll
            for (int r = 0; r < 4; ++r) kacc[n][mh][r] *= sc;
          kres[n] = redistC(kacc[n][0], kacc[n][1]);
        }
      }
      SCHED_FENCE();
      {
        f32x4 vacc[4][2];
        #pragma unroll
        for (int nv = 0; nv < 2; ++nv) {
          float bv = bkv[CDIM + 32 * h + 16 * nv + l15];
          #pragma unroll
          for (int m = 0; m < 4; ++m) vacc[m][nv] = f32x4{bv, bv, bv, bv};
        }
        #pragma unroll
        for (int ks = 0; ks < 6; ++ks) {
          short8 act[4];
          #pragma unroll
          for (int n = 0; n < 4; ++n)
            act[n] = *(const short8*)&sKV[(16 * n + l15) * LD + ks * 32 + 8 * l4];
          #pragma unroll
          for (int nv = 0; nv < 2; ++nv) {
            short8 vw = *(const short8*)&Wkvb[(size_t)(CDIM + 32 * h + 16 * nv + l15) * CDIM + ks * 32 + 8 * l4];
            #pragma unroll
            for (int m = 0; m < 4; ++m) vacc[m][nv] = MFMA(act[m], vw, vacc[m][nv]);
          }
        }
        #pragma unroll
        for (int cc = 0; cc < 2; ++cc)
          #pragma unroll
          for (int nv = 0; nv < 2; ++nv)
            av[cc][nv] = redistC(vacc[2 * cc][nv], vacc[2 * cc + 1][nv]);
      }
    }
    __syncthreads();   // A: sQX staging visible to all

    // ---- qproj from sQX (head-waves) ----
    short8 qres[4];
    if (wid < 6) {
      f32x4 qacc[4][2];
      #pragma unroll
      for (int mh = 0; mh < 2; ++mh) {
        float4 bk = *(const float4*)&bq[32 * h + 16 * mh + 4 * l4];
        #pragma unroll
        for (int n = 0; n < 4; ++n) qacc[n][mh] = f32x4{bk.x, bk.y, bk.z, bk.w};
      }
      #pragma unroll
      for (int ks = 0; ks < 6; ++ks) {
        short8 act[4];
        #pragma unroll
        for (int n = 0; n < 4; ++n)
          act[n] = *(const short8*)&sQX[(16 * n + l15) * LD + ks * 32 + 8 * l4];
        #pragma unroll
        for (int mh = 0; mh < 2; ++mh) {
          short8 qw = *(const short8*)&Wqb[(size_t)(32 * h + 16 * mh + l15) * CDIM + ks * 32 + 8 * l4];
          #pragma unroll
          for (int n = 0; n < 4; ++n) qacc[n][mh] = MFMA(qw, act[n], qacc[n][mh]);
        }
      }
      #pragma unroll
      for (int n = 0; n < 4; ++n) {
        float ss = 0.f;
        #pragma unroll
        for (int mh = 0; mh < 2; ++mh)
          #pragma unroll
          for (int r = 0; r < 4; ++r) ss += qacc[n][mh][r] * qacc[n][mh][r];
        ss += __shfl_xor(ss, 16);
        ss += __shfl_xor(ss, 32);
        float sc = SCALE / fmaxf(sqrtf(ss), EPSF);
        #pragma unroll
        for (int mh = 0; mh < 2; ++mh)
          #pragma unroll
          for (int r = 0; r < 4; ++r) qacc[n][mh][r] *= sc;
        qres[n] = redistC(qacc[n][0], qacc[n][1]);
      }
    }
    __syncthreads();   // B: all qproj reads of sQX done

    // ---- in-register attention; x -> sQX (over dead staging) ----
    if (wid < 6) {
      #pragma unroll
      for (int t = 0; t < 4; ++t) {
        f32x4 c[4];
        #pragma unroll
        for (int n = 0; n < 4; ++n) {
          f32x4 z = f32x4{0.f, 0.f, 0.f, 0.f};
          c[n] = MFMA(kres[n], qres[t], z);
        }
        float mx = c[0][0];
        #pragma unroll
        for (int n = 0; n < 4; ++n)
          #pragma unroll
          for (int r = 0; r < 4; ++r) mx = fmaxf(mx, c[n][r]);
        mx = fmaxf(mx, __shfl_xor(mx, 16));
        mx = fmaxf(mx, __shfl_xor(mx, 32));
        float sum = 0.f;
        #pragma unroll
        for (int n = 0; n < 4; ++n)
          #pragma unroll
          for (int r = 0; r < 4; ++r) { c[n][r] = __expf(c[n][r] - mx); sum += c[n][r]; }
        sum += __shfl_xor(sum, 16);
        sum += __shfl_xor(sum, 32);
        const float inv = 1.0f / sum;
        #pragma unroll
        for (int n = 0; n < 4; ++n)
          #pragma unroll
          for (int r = 0; r < 4; ++r) c[n][r] *= inv;
        short8 pa0 = redistC(c[0], c[1]);
        short8 pa1 = redistC(c[2], c[3]);
        f32x4 cx0 = f32x4{0.f, 0.f, 0.f, 0.f};
        f32x4 cx1 = f32x4{0.f, 0.f, 0.f, 0.f};
        cx0 = MFMA(av[0][0], pa0, cx0);
        cx0 = MFMA(av[1][0], pa1, cx0);
        cx1 = MFMA(av[0][1], pa0, cx1);
        cx1 = MFMA(av[1][1], pa1, cx1);
        short8 xf = redistC(cx0, cx1);
        *(short8*)&sQX[(16 * t + l15) * LD + h * 32 + 8 * l4] = xf;
      }
    }
    __syncthreads();   // C: x ready

    // ---- out-proj (reads sQX); prefetch next window's qx into regs first ----
    {
      if (w + 1 < tile_num) {
        const float4* gq = (const float4*)(qx + qoff + (size_t)BKV * (64 * CDIM));
        #pragma unroll
        for (int t = 0; t < 6; ++t) pre[t] = gq[tid + t * TPB];
      }
      {
        const int n0 = wid;
        f32x4 oacc[4];
        float bv = bp[n0 * 16 + l15];
        #pragma unroll
        for (int m = 0; m < 4; ++m) oacc[m] = f32x4{bv, bv, bv, bv};
        #pragma unroll
        for (int ks = 0; ks < 6; ++ks) {
          short8 pw = *(const short8*)&Wpb[(size_t)(n0 * 16 + l15) * CDIM + ks * 32 + 8 * l4];
          #pragma unroll
          for (int m = 0; m < 4; ++m) {
            short8 xa = *(const short8*)&sQX[(16 * m + l15) * LD + ks * 32 + 8 * l4];
            oacc[m] = MFMA(xa, pw, oacc[m]);
          }
        }
        #pragma unroll
        for (int m = 0; m < 4; ++m)
          #pragma unroll
          for (int r = 0; r < 4; ++r)
            out[qoff + (size_t)(16 * m + 4 * l4 + r) * CDIM + n0 * 16 + l15] = oacc[m][r];
      }
      SCHED_FENCE();
      if (wid >= 4) {
        const int n1 = wid + 4;
        f32x4 oacc[4];
        float bv = bp[n1 * 16 + l15];
        #pragma unroll
        for (int m = 0; m < 4; ++m) oacc[m] = f32x4{bv, bv, bv, bv};
        #pragma unroll
        for (int ks = 0; ks < 6; ++ks) {
          short8 pw = *(const short8*)&Wpb[(size_t)(n1 * 16 + l15) * CDIM + ks * 32 + 8 * l4];
          #pragma unroll
          for (int m = 0; m < 4; ++m) {
            short8 xa = *(const short8*)&sQX[(16 * m + l15) * LD + ks * 32 + 8 * l4];
            oacc[m] = MFMA(xa, pw, oacc[m]);
          }
        }
        #pragma unroll
        for (int m = 0; m < 4; ++m)
          #pragma unroll
          for (int r = 0; r < 4; ++r)
            out[qoff + (size_t)(16 * m + 4 * l4 + r) * CDIM + n1 * 16 + l15] = oacc[m][r];
      }
    }
    __syncthreads();   // D: sQX reads done before next loop-top overwrites
  }
}

extern "C" void kernel_launch(void* const* d_in, const int* in_sizes, int n_in,
                              void* d_out, int out_size, void* d_ws, size_t ws_size,
                              hipStream_t stream) {
  const float* qx  = (const float*)d_in[0];
  const float* kvx = (const float*)d_in[1];
  const float* pos = (const float*)d_in[2];
  const float* Wq  = (const float*)d_in[3];
  const float* bq  = (const float*)d_in[4];
  const float* Wkv = (const float*)d_in[5];
  const float* bkv = (const float*)d_in[6];
  const float* Wp  = (const float*)d_in[7];
  const float* bp  = (const float*)d_in[8];
  float* out = (float*)d_out;
  unsigned short* wsb = (unsigned short*)d_ws;

  const int BQ  = in_sizes[0] / (64 * CDIM);
  const int BKV = in_sizes[1] / (64 * CDIM);
  const int tile_num = BQ / BKV;

  const int ncvt = NWQ + NWKV + NWP;
  cvt_weights<<<(ncvt + 255) / 256, 256, 0, stream>>>(Wq, Wkv, Wp, wsb);

  wa_v15<<<BKV, TPB, 0, stream>>>(qx, kvx, pos, bq, bkv, bp,
                                  wsb, wsb + NWQ, wsb + NWQ + NWKV, out, BKV, tile_num);
}

// Round 16
// 465.778 us; speedup vs baseline: 1.9460x; 1.9460x over previous
//
#include <hip/hip_runtime.h>
#include <hip/hip_bf16.h>

#define TPB   512
#define CDIM  192
#define LDA   200    // shorts; sA leading dim
#define LDK   200    // shorts; K region leading dim
#define LDVT  72     // shorts; Vt leading dim
#define LDST  200    // shorts; kv staging leading dim (== K region reuse)
#define VTOFF 12800  // shorts; Vt offset inside sU (after 64*LDK)
#define SCALE 0.07216878364870323f  // 1/sqrt(192)
#define EPSF  1e-12f

using short8 = __attribute__((ext_vector_type(8))) short;
using f32x4  = __attribute__((ext_vector_type(4))) float;
using us4    = __attribute__((ext_vector_type(4))) unsigned short;

__device__ __forceinline__ unsigned short hc(float f) {
  __hip_bfloat16 h = __float2bfloat16(f);
  unsigned short u; __builtin_memcpy(&u, &h, 2); return u;
}
__device__ __forceinline__ unsigned pack2(float x, float y) {
  return (unsigned)hc(x) | ((unsigned)hc(y) << 16);
}
__device__ __forceinline__ uint2 packa(f32x4 a) {
  return make_uint2(pack2(a[0], a[1]), pack2(a[2], a[3]));
}
#define MFMA(a, b, c) __builtin_amdgcn_mfma_f32_16x16x32_bf16((a), (b), (c), 0, 0, 0)
#define SCHED_FENCE() __builtin_amdgcn_sched_barrier(0)

// ---- pre-kernel: cast weights f32 -> bf16 into workspace ----
#define NWQ  36864
#define NWKV 73728
#define NWP  36864
__global__ void cvt_weights(const float* __restrict__ Wq, const float* __restrict__ Wkv,
                            const float* __restrict__ Wp, unsigned short* __restrict__ o) {
  int i = blockIdx.x * blockDim.x + threadIdx.x;
  if (i < NWQ) o[i] = hc(Wq[i]);
  else if (i < NWQ + NWKV) o[i] = hc(Wkv[i - NWQ]);
  else if (i < NWQ + NWKV + NWP) o[i] = hc(Wp[i - NWQ - NWKV]);
}

__global__ __launch_bounds__(TPB, 4) void wa_v16(
    const float* __restrict__ qx, const float* __restrict__ kvx,
    const float* __restrict__ pos,
    const float* __restrict__ bq, const float* __restrict__ bkv,
    const float* __restrict__ bp,
    const unsigned short* __restrict__ Wqb, const unsigned short* __restrict__ Wkvb,
    const unsigned short* __restrict__ Wpb,
    float* __restrict__ out, int BQ, int BKV)
{
  __shared__ __align__(16) unsigned short sA[64 * LDA];  // qx+pos stage -> Q -> x
  __shared__ __align__(16) unsigned short sU[26624];     // kv stage -> K  |  Vt

  const int tid = threadIdx.x;
  const int wid = tid >> 6;          // 0..7
  const int l15 = (tid & 63) & 15;
  const int l4  = (tid & 63) >> 4;

  // window remap: pair (w, w+BKV) 8 dispatch slots apart -> same XCD, kvx L2-hot
  int g = blockIdx.x;
  int w;
  if (BQ == 2 * BKV && (BKV & 7) == 0) {
    w = ((g >> 4) << 3) + (g & 7) + (((g >> 3) & 1) ? BKV : 0);
  } else {
    w = g;
  }
  const size_t qoff  = (size_t)w * (64 * CDIM);
  const size_t kvoff = (size_t)(w % BKV) * (64 * CDIM);

  const int srcA = l15 + 32 * (l4 & 1);
  const int srcB = srcA + 16;
  const int sel  = l4 >> 1;
  // validated: cA[r]=M[l15][base+4*l4+r], cB[r]=M[l15][base+16+4*l4+r]
  //        ->  frag[j] = M[l15][base + 8*l4 + j]  (bf16)
  auto redistC = [&](f32x4 cA, f32x4 cB) -> short8 {
    unsigned iA0 = pack2(cA[0], cA[1]), iA1 = pack2(cA[2], cA[3]);
    unsigned iB0 = pack2(cB[0], cB[1]), iB1 = pack2(cB[2], cB[3]);
    unsigned A00 = (unsigned)__shfl((int)iA0, srcA);
    unsigned A01 = (unsigned)__shfl((int)iA1, srcA);
    unsigned A10 = (unsigned)__shfl((int)iB0, srcA);
    unsigned A11 = (unsigned)__shfl((int)iB1, srcA);
    unsigned B00 = (unsigned)__shfl((int)iA0, srcB);
    unsigned B01 = (unsigned)__shfl((int)iA1, srcB);
    unsigned B10 = (unsigned)__shfl((int)iB0, srcB);
    unsigned B11 = (unsigned)__shfl((int)iB1, srcB);
    union { uint4 u; short8 s; } uu;
    uu.u.x = sel ? A10 : A00;
    uu.u.y = sel ? A11 : A01;
    uu.u.z = sel ? B10 : B00;
    uu.u.w = sel ? B11 : B01;
    return uu.s;
  };

  // ============ P1: coalesced staging ============
  {
    const float4* gq = (const float4*)(qx + qoff);
    const float4* p4 = (const float4*)pos;
    #pragma unroll
    for (int t = 0; t < 6; ++t) {
      int e = tid + t * TPB, row = e / 48, c4 = e % 48;
      float4 a = gq[e], p = p4[e];
      us4 wq;
      wq.x = hc(a.x + p.x); wq.y = hc(a.y + p.y); wq.z = hc(a.z + p.z); wq.w = hc(a.w + p.w);
      *(us4*)&sA[row * LDA + c4 * 4] = wq;
    }
    const float4* gk = (const float4*)(kvx + kvoff);
    #pragma unroll
    for (int t = 0; t < 6; ++t) {
      int e = tid + t * TPB, row = e / 48, c4 = e % 48;
      float4 k = gk[e];
      us4 wk; wk.x = hc(k.x); wk.y = hc(k.y); wk.z = hc(k.z); wk.w = hc(k.w);
      *(us4*)&sU[row * LDST + c4 * 4] = wk;
    }
  }
  __syncthreads();

  // ---- task bodies (reuse-4) ----
  auto kproj = [&](int h, short8* kres) {
    f32x4 kacc[4][2];
    #pragma unroll
    for (int mh = 0; mh < 2; ++mh) {
      float4 bk = *(const float4*)&bkv[32 * h + 16 * mh + 4 * l4];
      #pragma unroll
      for (int n = 0; n < 4; ++n) kacc[n][mh] = f32x4{bk.x, bk.y, bk.z, bk.w};
    }
    #pragma unroll
    for (int ks = 0; ks < 6; ++ks) {
      short8 act[4];
      #pragma unroll
      for (int n = 0; n < 4; ++n)
        act[n] = *(const short8*)&sU[(16 * n + l15) * LDST + ks * 32 + 8 * l4];
      #pragma unroll
      for (int mh = 0; mh < 2; ++mh) {
        short8 kw = *(const short8*)&Wkvb[(size_t)(32 * h + 16 * mh + l15) * CDIM + ks * 32 + 8 * l4];
        #pragma unroll
        for (int n = 0; n < 4; ++n) kacc[n][mh] = MFMA(kw, act[n], kacc[n][mh]);
      }
    }
    #pragma unroll
    for (int n = 0; n < 4; ++n) {
      float ss = 0.f;
      #pragma unroll
      for (int mh = 0; mh < 2; ++mh)
        #pragma unroll
        for (int r = 0; r < 4; ++r) ss += kacc[n][mh][r] * kacc[n][mh][r];
      ss += __shfl_xor(ss, 16);
      ss += __shfl_xor(ss, 32);
      float sc = 1.0f / fmaxf(sqrtf(ss), EPSF);
      #pragma unroll
      for (int mh = 0; mh < 2; ++mh)
        #pragma unroll
        for (int r = 0; r < 4; ++r) kacc[n][mh][r] *= sc;
      kres[n] = redistC(kacc[n][0], kacc[n][1]);
    }
  };
  // half V-projection: one 16-col v-tile (head h, half nv); writes through to Vt
  auto vhalf = [&](int h, int nv) {
    f32x4 vacc[4];
    {
      float bv = bkv[CDIM + 32 * h + 16 * nv + l15];
      #pragma unroll
      for (int m = 0; m < 4; ++m) vacc[m] = f32x4{bv, bv, bv, bv};
    }
    #pragma unroll
    for (int ks = 0; ks < 6; ++ks) {
      short8 vw = *(const short8*)&Wkvb[(size_t)(CDIM + 32 * h + 16 * nv + l15) * CDIM + ks * 32 + 8 * l4];
      #pragma unroll
      for (int m = 0; m < 4; ++m) {
        short8 act = *(const short8*)&sU[(16 * m + l15) * LDST + ks * 32 + 8 * l4];
        vacc[m] = MFMA(act, vw, vacc[m]);
      }
    }
    #pragma unroll
    for (int m = 0; m < 4; ++m)
      *(uint2*)&sU[VTOFF + (32 * h + 16 * nv + l15) * LDVT + 16 * m + 4 * l4] = packa(vacc[m]);
  };
  auto qproj = [&](int h, short8* qres) {
    f32x4 qacc[4][2];
    #pragma unroll
    for (int mh = 0; mh < 2; ++mh) {
      float4 bk = *(const float4*)&bq[32 * h + 16 * mh + 4 * l4];
      #pragma unroll
      for (int n = 0; n < 4; ++n) qacc[n][mh] = f32x4{bk.x, bk.y, bk.z, bk.w};
    }
    #pragma unroll
    for (int ks = 0; ks < 6; ++ks) {
      short8 act[4];
      #pragma unroll
      for (int n = 0; n < 4; ++n)
        act[n] = *(const short8*)&sA[(16 * n + l15) * LDA + ks * 32 + 8 * l4];
      #pragma unroll
      for (int mh = 0; mh < 2; ++mh) {
        short8 qw = *(const short8*)&Wqb[(size_t)(32 * h + 16 * mh + l15) * CDIM + ks * 32 + 8 * l4];
        #pragma unroll
        for (int n = 0; n < 4; ++n) qacc[n][mh] = MFMA(qw, act[n], qacc[n][mh]);
      }
    }
    #pragma unroll
    for (int n = 0; n < 4; ++n) {
      float ss = 0.f;
      #pragma unroll
      for (int mh = 0; mh < 2; ++mh)
        #pragma unroll
        for (int r = 0; r < 4; ++r) ss += qacc[n][mh][r] * qacc[n][mh][r];
      ss += __shfl_xor(ss, 16);
      ss += __shfl_xor(ss, 32);
      float sc = SCALE / fmaxf(sqrtf(ss), EPSF);
      #pragma unroll
      for (int mh = 0; mh < 2; ++mh)
        #pragma unroll
        for (int r = 0; r < 4; ++r) qacc[n][mh][r] *= sc;
      qres[n] = redistC(qacc[n][0], qacc[n][1]);
    }
  };

  // ============ P2: balanced — waves 0-5: kproj + 1 half-V; waves 6,7: 3 half-V ============
  short8 kres[4];
  const bool hasK = (wid < 6);
  if (hasK) {
    kproj(wid, kres);
    SCHED_FENCE();
    vhalf(wid >> 1, wid & 1);         // half-tasks 0..5 (heads 0..2)
  } else {
    const int t0 = 6 + (wid - 6) * 3; // 6 or 9 -> half-tasks 6..11 (heads 3..5)
    vhalf(t0 >> 1, t0 & 1);
    SCHED_FENCE();
    vhalf((t0 + 1) >> 1, (t0 + 1) & 1);
    SCHED_FENCE();
    vhalf((t0 + 2) >> 1, (t0 + 2) & 1);
  }
  __syncthreads();

  // ============ P3: write K; Q tasks (waves 0..5) ============
  if (hasK) {
    #pragma unroll
    for (int n = 0; n < 4; ++n)
      *(short8*)&sU[(16 * n + l15) * LDK + wid * 32 + 8 * l4] = kres[n];
  }
  SCHED_FENCE();
  short8 qres[4];
  if (wid < 6) qproj(wid, qres);
  __syncthreads();

  // ============ P4: write Q ============
  if (wid < 6) {
    #pragma unroll
    for (int n = 0; n < 4; ++n)
      *(short8*)&sA[(16 * n + l15) * LDA + wid * 32 + 8 * l4] = qres[n];
  }
  __syncthreads();

  // ============ P5: attention — tile = wid&3, heads 3*(wid>>2)..+2; max-free softmax ============
  {
    const int t  = wid & 3;
    const int h0 = 3 * (wid >> 2);
    #pragma unroll
    for (int i = 0; i < 3; ++i) {
      const int hh = h0 + i;
      short8 qb = *(const short8*)&sA[(16 * t + l15) * LDA + hh * 32 + 8 * l4];
      f32x4 c[4];
      #pragma unroll
      for (int n = 0; n < 4; ++n) {
        short8 ak = *(const short8*)&sU[(16 * n + l15) * LDK + hh * 32 + 8 * l4];
        f32x4 z = f32x4{0.f, 0.f, 0.f, 0.f};
        c[n] = MFMA(ak, qb, z);
      }
      // |S| <= SCALE (unit vectors) -> exp never overflows; softmax is shift-invariant
      float sum = 0.f;
      #pragma unroll
      for (int n = 0; n < 4; ++n)
        #pragma unroll
        for (int r = 0; r < 4; ++r) { c[n][r] = __expf(c[n][r]); sum += c[n][r]; }
      sum += __shfl_xor(sum, 16);
      sum += __shfl_xor(sum, 32);
      const float inv = 1.0f / sum;
      #pragma unroll
      for (int n = 0; n < 4; ++n)
        #pragma unroll
        for (int r = 0; r < 4; ++r) c[n][r] *= inv;
      short8 pa0 = redistC(c[0], c[1]);
      short8 pa1 = redistC(c[2], c[3]);
      f32x4 cx0 = f32x4{0.f, 0.f, 0.f, 0.f};
      f32x4 cx1 = f32x4{0.f, 0.f, 0.f, 0.f};
      {
        short8 av00 = *(const short8*)&sU[VTOFF + (hh * 32 + l15) * LDVT + 8 * l4];
        short8 av01 = *(const short8*)&sU[VTOFF + (hh * 32 + l15) * LDVT + 32 + 8 * l4];
        cx0 = MFMA(av00, pa0, cx0);
        cx0 = MFMA(av01, pa1, cx0);
        short8 av10 = *(const short8*)&sU[VTOFF + (hh * 32 + 16 + l15) * LDVT + 8 * l4];
        short8 av11 = *(const short8*)&sU[VTOFF + (hh * 32 + 16 + l15) * LDVT + 32 + 8 * l4];
        cx1 = MFMA(av10, pa0, cx1);
        cx1 = MFMA(av11, pa1, cx1);
      }
      short8 xf = redistC(cx0, cx1);
      *(short8*)&sA[(16 * t + l15) * LDA + hh * 32 + 8 * l4] = xf;
    }
  }
  __syncthreads();

  // ============ P6: out-proj — n = wid (+8 for waves 0..3), reuse-4 ============
  {
    {
      const int n = wid;
      f32x4 oacc[4];
      float bv = bp[n * 16 + l15];
      #pragma unroll
      for (int m = 0; m < 4; ++m) oacc[m] = f32x4{bv, bv, bv, bv};
      #pragma unroll
      for (int ks = 0; ks < 6; ++ks) {
        short8 pw = *(const short8*)&Wpb[(size_t)(n * 16 + l15) * CDIM + ks * 32 + 8 * l4];
        #pragma unroll
        for (int m = 0; m < 4; ++m) {
          short8 xa = *(const short8*)&sA[(16 * m + l15) * LDA + ks * 32 + 8 * l4];
          oacc[m] = MFMA(xa, pw, oacc[m]);
        }
      }
      #pragma unroll
      for (int m = 0; m < 4; ++m)
        #pragma unroll
        for (int r = 0; r < 4; ++r)
          out[qoff + (size_t)(16 * m + 4 * l4 + r) * CDIM + n * 16 + l15] = oacc[m][r];
    }
    SCHED_FENCE();
    if (wid < 4) {
      const int n = wid + 8;
      f32x4 oacc[4];
      float bv = bp[n * 16 + l15];
      #pragma unroll
      for (int m = 0; m < 4; ++m) oacc[m] = f32x4{bv, bv, bv, bv};
      #pragma unroll
      for (int ks = 0; ks < 6; ++ks) {
        short8 pw = *(const short8*)&Wpb[(size_t)(n * 16 + l15) * CDIM + ks * 32 + 8 * l4];
        #pragma unroll
        for (int m = 0; m < 4; ++m) {
          short8 xa = *(const short8*)&sA[(16 * m + l15) * LDA + ks * 32 + 8 * l4];
          oacc[m] = MFMA(xa, pw, oacc[m]);
        }
      }
      #pragma unroll
      for (int m = 0; m < 4; ++m)
        #pragma unroll
        for (int r = 0; r < 4; ++r)
          out[qoff + (size_t)(16 * m + 4 * l4 + r) * CDIM + n * 16 + l15] = oacc[m][r];
    }
  }
}

extern "C" void kernel_launch(void* const* d_in, const int* in_sizes, int n_in,
                              void* d_out, int out_size, void* d_ws, size_t ws_size,
                              hipStream_t stream) {
  const float* qx  = (const float*)d_in[0];
  const float* kvx = (const float*)d_in[1];
  const float* pos = (const float*)d_in[2];
  const float* Wq  = (const float*)d_in[3];
  const float* bq  = (const float*)d_in[4];
  const float* Wkv = (const float*)d_in[5];
  const float* bkv = (const float*)d_in[6];
  const float* Wp  = (const float*)d_in[7];
  const float* bp  = (const float*)d_in[8];
  float* out = (float*)d_out;
  unsigned short* wsb = (unsigned short*)d_ws;

  const int BQ  = in_sizes[0] / (64 * CDIM);
  const int BKV = in_sizes[1] / (64 * CDIM);

  const int ncvt = NWQ + NWKV + NWP;
  cvt_weights<<<(ncvt + 255) / 256, 256, 0, stream>>>(Wq, Wkv, Wp, wsb);

  wa_v16<<<BQ, TPB, 0, stream>>>(qx, kvx, pos, bq, bkv, bp,
                                 wsb, wsb + NWQ, wsb + NWQ + NWKV, out, BQ, BKV);
}